// Round 8
// baseline (529.081 us; speedup 1.0000x reference)
//
#include <hip/hip_runtime.h>
#include <math.h>

#define BN_EPS 1e-5f

// ---------------- math helpers ----------------
__device__ __forceinline__ float fast_exp2(float a) {
#if __has_builtin(__builtin_amdgcn_exp2f)
    return __builtin_amdgcn_exp2f(a);
#else
    return __expf(a * 0.6931471805599453f);
#endif
}
__device__ __forceinline__ float fast_cosrev(float r) {
#if __has_builtin(__builtin_amdgcn_fractf)
    r = __builtin_amdgcn_fractf(r);
#else
    r = r - floorf(r);
#endif
#if __has_builtin(__builtin_amdgcn_cosf)
    return __builtin_amdgcn_cosf(r);
#else
    return __cosf(r * 6.283185307179586f);
#endif
}
// psi(u) = cos(5u)*exp(-u^2/2)   (validated r1-r7: absmax <= 0.031)
__device__ __forceinline__ float psi_hw(float u) {
    const float KM = 0.84932181f;            // sqrt(0.5*log2(e))
    const float KC = 0.7957747154594767f;    // 5/(2*pi)
    const float m = u * KM;
    return fast_cosrev(u * KC) * fast_exp2(-(m * m));
}

typedef __bf16 bf16x8 __attribute__((ext_vector_type(8)));
typedef float  f32x4  __attribute__((ext_vector_type(4)));

// =====================================================================
// fused_kan: entire op in ONE kernel.
//   grid = (B/64)*(O/64) <= 512 blocks, 256 threads. 2 blocks/CU co-resident
//   (35 KB LDS, 8 waves/CU -- capacity-safe; barrier pattern validated r4).
//   phase 1: block-local uniformity check; fast bf16-MFMA GEMM (psi fused
//            in staging, r5-proven) or in-block general path; BN partials
//            to per-block slots via agent-scope release stores.
//   phase 2: grid barrier; per-block A,C from slots; BN applied IN REGISTERS;
//            single y write (no y round-trip, no bn_coef/bn_apply nodes).
// =====================================================================
__global__ __launch_bounds__(256)
void fused_kan(const float* __restrict__ x, const float* __restrict__ scale,
               const float* __restrict__ bias, const float* __restrict__ weight,
               const float* __restrict__ gamma, const float* __restrict__ beta,
               float* __restrict__ y, unsigned* __restrict__ bar,
               float* __restrict__ part_s, float* __restrict__ part_q,
               int B, int I, int O, int nob, int nblocks, int nb)
{
    __shared__ __align__(16) char smem[33280];   // union: bf16 tiles / f32 staging
    __shared__ float reds[4][64], redq[4][64];
    __shared__ float As[64], Cs[64];
    __shared__ int sbad;

    const int tid = threadIdx.x;
    const int ob  = blockIdx.x % nob;
    const int bb  = blockIdx.x / nob;
    const int O0  = ob * 64;
    const int B0  = bb * 64;
    const int lane = tid & 63;
    const int w    = tid >> 6;

    // ---- block-local uniformity check: rows O0..O0+63 vs row O0 (bitwise) ----
    unsigned bad = 0;
    {
        const uint4* s4 = (const uint4*)scale;
        const uint4* b4 = (const uint4*)bias;
        const int i4 = I >> 2;
        const size_t base = (size_t)O0 * i4;
        for (int idx = tid; idx < 64 * i4; idx += 256) {
            const int c = idx % i4;
            uint4 a  = s4[base + idx], a0 = s4[base + c];
            uint4 bv = b4[base + idx], b0 = b4[base + c];
            bad |= (a.x^a0.x)|(a.y^a0.y)|(a.z^a0.z)|(a.w^a0.w)
                 | (bv.x^b0.x)|(bv.y^b0.y)|(bv.z^b0.z)|(bv.w^b0.w);
        }
    }
    if (tid == 0) sbad = 0;
    __syncthreads();
    if (bad) atomicOr(&sbad, 1);
    __syncthreads();

    // quadrant/thread mappings
    const int wm  = w >> 1, wn = w & 1;
    const int m16 = lane & 15, kg = lane >> 4;
    const int og  = tid & 15, bg = tid >> 4;

    f32x4 accF[2][2] = {};   // fast path accumulators
    float accG[4][4] = {};   // general path accumulators

    if (sbad == 0) {
        // ================= fast path: psi fused into bf16 MFMA staging =================
        __bf16* Pl = (__bf16*)smem;          // [64][128] swizzled
        __bf16* Wl = Pl + 64 * 128;

        for (int ic = 0; ic < I; ic += 128) {
            __syncthreads();
            #pragma unroll
            for (int it = 0; it < 4; ++it) {
                const int idx = tid + it * 256;
                const int row = idx >> 4;
                const int kk  = (idx & 15) * 8;
                float4 s0 = *(const float4*)&scale[(size_t)O0 * I + ic + kk];
                float4 s1 = *(const float4*)&scale[(size_t)O0 * I + ic + kk + 4];
                float4 b0 = *(const float4*)&bias [(size_t)O0 * I + ic + kk];
                float4 b1 = *(const float4*)&bias [(size_t)O0 * I + ic + kk + 4];
                float4 x0 = *(const float4*)&x[(size_t)(B0 + row) * I + ic + kk];
                float4 x1 = *(const float4*)&x[(size_t)(B0 + row) * I + ic + kk + 4];
                float4 w0 = *(const float4*)&weight[(size_t)(O0 + row) * I + ic + kk];
                float4 w1 = *(const float4*)&weight[(size_t)(O0 + row) * I + ic + kk + 4];
                bf16x8 pv, wv;
                #pragma unroll
                for (int e = 0; e < 4; ++e) {
                    const float ra = __builtin_amdgcn_rcpf(((const float*)&s0)[e]);
                    pv[e] = (__bf16)psi_hw((((const float*)&x0)[e] - ((const float*)&b0)[e]) * ra);
                    wv[e] = (__bf16)((const float*)&w0)[e];
                    const float rb = __builtin_amdgcn_rcpf(((const float*)&s1)[e]);
                    pv[e + 4] = (__bf16)psi_hw((((const float*)&x1)[e] - ((const float*)&b1)[e]) * rb);
                    wv[e + 4] = (__bf16)((const float*)&w1)[e];
                }
                unsigned byte = (unsigned)(row * 256 + kk * 2);
                byte ^= (unsigned)((row & 7) << 4);
                *reinterpret_cast<bf16x8*>(reinterpret_cast<char*>(Pl) + byte) = pv;
                *reinterpret_cast<bf16x8*>(reinterpret_cast<char*>(Wl) + byte) = wv;
            }
            __syncthreads();

            #pragma unroll
            for (int ks = 0; ks < 4; ++ks) {
                bf16x8 a[2], b[2];
                #pragma unroll
                for (int mi = 0; mi < 2; ++mi) {
                    const int row = wm * 32 + mi * 16 + m16;
                    unsigned byte = (unsigned)(row * 256 + ks * 64 + kg * 16);
                    byte ^= (unsigned)((row & 7) << 4);
                    a[mi] = *reinterpret_cast<const bf16x8*>(reinterpret_cast<const char*>(Pl) + byte);
                }
                #pragma unroll
                for (int ni = 0; ni < 2; ++ni) {
                    const int row = wn * 32 + ni * 16 + m16;
                    unsigned byte = (unsigned)(row * 256 + ks * 64 + kg * 16);
                    byte ^= (unsigned)((row & 7) << 4);
                    b[ni] = *reinterpret_cast<const bf16x8*>(reinterpret_cast<const char*>(Wl) + byte);
                }
                #pragma unroll
                for (int mi = 0; mi < 2; ++mi)
                    #pragma unroll
                    for (int ni = 0; ni < 2; ++ni)
                        accF[mi][ni] = __builtin_amdgcn_mfma_f32_16x16x32_bf16(
                            a[mi], b[ni], accF[mi][ni], 0, 0, 0);
            }
        }

        // ---- BN partials -> per-block slots (release/agent) ----
        float s0 = 0.f, s1 = 0.f, q0 = 0.f, q1 = 0.f;
        #pragma unroll
        for (int mi = 0; mi < 2; ++mi)
            #pragma unroll
            for (int r = 0; r < 4; ++r) {
                const float v0 = accF[mi][0][r], v1 = accF[mi][1][r];
                s0 += v0; q0 += v0 * v0;
                s1 += v1; q1 += v1 * v1;
            }
        s0 += __shfl_xor(s0, 16); s0 += __shfl_xor(s0, 32);
        q0 += __shfl_xor(q0, 16); q0 += __shfl_xor(q0, 32);
        s1 += __shfl_xor(s1, 16); s1 += __shfl_xor(s1, 32);
        q1 += __shfl_xor(q1, 16); q1 += __shfl_xor(q1, 32);
        if (lane < 16) {
            reds[w][m16]      = s0;  redq[w][m16]      = q0;
            reds[w][16 + m16] = s1;  redq[w][16 + m16] = q1;
        }
        __syncthreads();
        if (tid < 64) {
            const int wn2 = tid >> 5;
            const int cw  = tid & 31;
            const float ss = reds[wn2][cw] + reds[2 + wn2][cw];
            const float qq = redq[wn2][cw] + redq[2 + wn2][cw];
            __hip_atomic_store(&part_s[(size_t)bb * O + O0 + tid], ss,
                               __ATOMIC_RELEASE, __HIP_MEMORY_SCOPE_AGENT);
            __hip_atomic_store(&part_q[(size_t)bb * O + O0 + tid], qq,
                               __ATOMIC_RELEASE, __HIP_MEMORY_SCOPE_AGENT);
        }
    } else {
        // ================= general path: per-(o,i) scale/bias =================
        float* xs  = (float*)smem;           // [64][33]
        float* ssm = xs + 64 * 33;           // [32][64] transposed
        float* bsm = ssm + 32 * 64;
        float* wsm = bsm + 32 * 64;

        for (int ic = 0; ic < I; ic += 32) {
            __syncthreads();
            for (int idx = tid; idx < 512; idx += 256) {
                const int row = idx >> 3;
                const int c4  = (idx & 7) * 4;
                float4 vv = *(const float4*)&x[(size_t)(B0 + row) * I + ic + c4];
                xs[row * 33 + c4 + 0] = vv.x;
                xs[row * 33 + c4 + 1] = vv.y;
                xs[row * 33 + c4 + 2] = vv.z;
                xs[row * 33 + c4 + 3] = vv.w;
            }
            for (int idx = tid; idx < 512; idx += 256) {
                const int o  = idx >> 3;
                const int c4 = (idx & 7) * 4;
                const size_t g = (size_t)(O0 + o) * I + ic + c4;
                float4 sv = *(const float4*)&scale[g];
                float4 bv = *(const float4*)&bias[g];
                float4 wv = *(const float4*)&weight[g];
                #pragma unroll
                for (int e = 0; e < 4; ++e) {
                    ssm[(c4 + e) * 64 + o] = ((const float*)&sv)[e];
                    bsm[(c4 + e) * 64 + o] = ((const float*)&bv)[e];
                    wsm[(c4 + e) * 64 + o] = ((const float*)&wv)[e];
                }
            }
            __syncthreads();

            for (int k = 0; k < 32; ++k) {
                float xv[4];
                #pragma unroll
                for (int t = 0; t < 4; ++t) xv[t] = xs[(bg * 4 + t) * 33 + k];
                #pragma unroll
                for (int j = 0; j < 4; ++j) {
                    const int o = og * 4 + j;
                    const float sv = ssm[k * 64 + o];
                    const float bv = bsm[k * 64 + o];
                    const float wv = wsm[k * 64 + o];
                    const float rv = __builtin_amdgcn_rcpf(sv);
                    #pragma unroll
                    for (int t = 0; t < 4; ++t) {
                        const float u = (xv[t] - bv) * rv;
                        accG[t][j] = fmaf(psi_hw(u), wv, accG[t][j]);
                    }
                }
            }
        }

        float s[4], q[4];
        #pragma unroll
        for (int j = 0; j < 4; ++j) {
            s[j] = accG[0][j] + accG[1][j] + accG[2][j] + accG[3][j];
            q[j] = accG[0][j]*accG[0][j] + accG[1][j]*accG[1][j]
                 + accG[2][j]*accG[2][j] + accG[3][j]*accG[3][j];
            s[j] += __shfl_xor(s[j], 16); s[j] += __shfl_xor(s[j], 32);
            q[j] += __shfl_xor(q[j], 16); q[j] += __shfl_xor(q[j], 32);
        }
        if (lane < 16) {
            #pragma unroll
            for (int j = 0; j < 4; ++j) {
                reds[w][og * 4 + j] = s[j];
                redq[w][og * 4 + j] = q[j];
            }
        }
        __syncthreads();
        if (tid < 64) {
            const float ss = reds[0][tid] + reds[1][tid] + reds[2][tid] + reds[3][tid];
            const float qq = redq[0][tid] + redq[1][tid] + redq[2][tid] + redq[3][tid];
            __hip_atomic_store(&part_s[(size_t)bb * O + O0 + tid], ss,
                               __ATOMIC_RELEASE, __HIP_MEMORY_SCOPE_AGENT);
            __hip_atomic_store(&part_q[(size_t)bb * O + O0 + tid], qq,
                               __ATOMIC_RELEASE, __HIP_MEMORY_SCOPE_AGENT);
        }
    }

    // ---- grid barrier (r4-validated pattern; all blocks co-resident) ----
    __syncthreads();
    if (tid == 0) {
        __hip_atomic_fetch_add(bar, 1u, __ATOMIC_ACQ_REL, __HIP_MEMORY_SCOPE_AGENT);
        while (__hip_atomic_load(bar, __ATOMIC_ACQUIRE, __HIP_MEMORY_SCOPE_AGENT) < (unsigned)nblocks)
            __builtin_amdgcn_s_sleep(2);
    }
    __syncthreads();

    // ---- phase 2: A,C for this block's 64 o's from all nb slots ----
    {
        const int ol = tid & 63;
        const int st = tid >> 6;          // 4 stripes over nb
        const int per = nb >> 2;          // host guarantees nb % 4 == 0
        float s = 0.f, q = 0.f;
        for (int b2 = st * per; b2 < (st + 1) * per; ++b2) {
            s += __hip_atomic_load(&part_s[(size_t)b2 * O + O0 + ol],
                                   __ATOMIC_ACQUIRE, __HIP_MEMORY_SCOPE_AGENT);
            q += __hip_atomic_load(&part_q[(size_t)b2 * O + O0 + ol],
                                   __ATOMIC_ACQUIRE, __HIP_MEMORY_SCOPE_AGENT);
        }
        reds[st][ol] = s;
        redq[st][ol] = q;
    }
    __syncthreads();
    if (tid < 64) {
        const float s = reds[0][tid] + reds[1][tid] + reds[2][tid] + reds[3][tid];
        const float q = redq[0][tid] + redq[1][tid] + redq[2][tid] + redq[3][tid];
        const float invB = 1.0f / (float)B;
        const float m = s * invB;
        const float v = fmaxf(q * invB - m * m, 0.f);
        const float a = gamma[O0 + tid] * rsqrtf(v + BN_EPS);
        As[tid] = a;
        Cs[tid] = fmaf(-m, a, beta[O0 + tid]);
    }
    __syncthreads();

    // ---- apply BN in registers, single y write ----
    if (sbad == 0) {
        #pragma unroll
        for (int ni = 0; ni < 2; ++ni) {
            const int cl = wn * 32 + ni * 16 + m16;
            const float a = As[cl], c = Cs[cl];
            #pragma unroll
            for (int mi = 0; mi < 2; ++mi) {
                const int rbase = B0 + wm * 32 + mi * 16 + kg * 4;
                #pragma unroll
                for (int r = 0; r < 4; ++r)
                    y[(size_t)(rbase + r) * O + O0 + cl] = fmaf(accF[mi][ni][r], a, c);
            }
        }
    } else {
        const float a0 = As[og*4+0], a1 = As[og*4+1], a2 = As[og*4+2], a3 = As[og*4+3];
        const float c0 = Cs[og*4+0], c1 = Cs[og*4+1], c2 = Cs[og*4+2], c3 = Cs[og*4+3];
        #pragma unroll
        for (int t = 0; t < 4; ++t) {
            float4 r;
            r.x = fmaf(accG[t][0], a0, c0);
            r.y = fmaf(accG[t][1], a1, c1);
            r.z = fmaf(accG[t][2], a2, c2);
            r.w = fmaf(accG[t][3], a3, c3);
            *(float4*)&y[(size_t)(B0 + bg * 4 + t) * O + O0 + og * 4] = r;
        }
    }
}

// =====================================================================
// Shape fallback (non-divisible): round-1 proven general kernel + BN chain
// =====================================================================
constexpr int BT  = 128;
constexpr int OT  = 32;
constexpr int IC  = 64;
constexpr int TPB = 512;
constexpr int LDR = IC + 4;

__global__ __launch_bounds__(TPB, 4)
void kan_forward(const float* __restrict__ x, const float* __restrict__ scale,
                 const float* __restrict__ bias, const float* __restrict__ weight,
                 float* __restrict__ y, float* __restrict__ gsum,
                 float* __restrict__ gsq, int B, int I, int O)
{
    __shared__ __align__(16) float xs[BT][LDR];
    __shared__ __align__(16) float pr[OT][LDR];
    __shared__ __align__(16) float pc[OT][LDR];
    __shared__ __align__(16) float pw[OT][LDR];

    const int tid = threadIdx.x;
    const int og  = tid & 15;
    const int bg  = tid >> 4;
    const int O0  = blockIdx.x * OT;
    const int B0  = blockIdx.y * BT;

    float acc[4][2] = {{0.f,0.f},{0.f,0.f},{0.f,0.f},{0.f,0.f}};

    for (int ic = 0; ic < I; ic += IC) {
        __syncthreads();
        for (int r = tid; r < BT * (IC/4); r += TPB) {
            const int row = r >> 4;
            const int c4  = (r & 15) * 4;
            float4 v = *(const float4*)&x[(size_t)(B0+row)*I + ic + c4];
            *(float4*)&xs[row][c4] = v;
        }
        for (int r = tid; r < OT * (IC/4); r += TPB) {
            const int row = r >> 4;
            const int c4  = (r & 15) * 4;
            const size_t g = (size_t)(O0+row)*I + ic + c4;
            float4 sv = *(const float4*)&scale[g];
            float4 bv = *(const float4*)&bias[g];
            float4 wv = *(const float4*)&weight[g];
            float4 rv, cv;
            rv.x = 1.0f/sv.x; rv.y = 1.0f/sv.y; rv.z = 1.0f/sv.z; rv.w = 1.0f/sv.w;
            cv.x = -bv.x*rv.x; cv.y = -bv.y*rv.y; cv.z = -bv.z*rv.z; cv.w = -bv.w*rv.w;
            *(float4*)&pr[row][c4] = rv;
            *(float4*)&pc[row][c4] = cv;
            *(float4*)&pw[row][c4] = wv;
        }
        __syncthreads();

        #pragma unroll 2
        for (int i = 0; i < IC; i += 4) {
            float4 xv[4];
            #pragma unroll
            for (int k = 0; k < 4; ++k)
                xv[k] = *(const float4*)&xs[bg*4+k][i];
            #pragma unroll
            for (int j = 0; j < 2; ++j) {
                const int o = og*2 + j;
                const float4 rv = *(const float4*)&pr[o][i];
                const float4 cv = *(const float4*)&pc[o][i];
                const float4 wv = *(const float4*)&pw[o][i];
                #pragma unroll
                for (int k = 0; k < 4; ++k) {
                    #pragma unroll
                    for (int e = 0; e < 4; ++e) {
                        const float u = fmaf(((const float*)&xv[k])[e],
                                             ((const float*)&rv)[e], ((const float*)&cv)[e]);
                        acc[k][j] = fmaf(psi_hw(u), ((const float*)&wv)[e], acc[k][j]);
                    }
                }
            }
        }
    }

    #pragma unroll
    for (int k = 0; k < 4; ++k) {
        float2 v = make_float2(acc[k][0], acc[k][1]);
        *(float2*)&y[(size_t)(B0 + bg*4 + k)*O + O0 + og*2] = v;
    }

    float s[2], q[2];
    #pragma unroll
    for (int j = 0; j < 2; ++j) {
        s[j] = acc[0][j]+acc[1][j]+acc[2][j]+acc[3][j];
        q[j] = acc[0][j]*acc[0][j]+acc[1][j]*acc[1][j]
             + acc[2][j]*acc[2][j]+acc[3][j]*acc[3][j];
        s[j] += __shfl_xor(s[j], 16); s[j] += __shfl_xor(s[j], 32);
        q[j] += __shfl_xor(q[j], 16); q[j] += __shfl_xor(q[j], 32);
    }
    __syncthreads();
    float* red = &xs[0][0];
    const int wave = tid >> 6;
    const int lane = tid & 63;
    if (lane < 16) {
        red[      wave*32 + og*2 + 0] = s[0];
        red[      wave*32 + og*2 + 1] = s[1];
        red[256 + wave*32 + og*2 + 0] = q[0];
        red[256 + wave*32 + og*2 + 1] = q[1];
    }
    __syncthreads();
    if (tid < OT) {
        float ss = 0.f, qq = 0.f;
        #pragma unroll
        for (int w2 = 0; w2 < TPB/64; ++w2) {
            ss += red[      w2*32 + tid];
            qq += red[256 + w2*32 + tid];
        }
        atomicAdd(&gsum[O0 + tid], ss);
        atomicAdd(&gsq [O0 + tid], qq);
    }
}

__global__ void bn_coef(const float* __restrict__ ps, const float* __restrict__ pq,
                        const float* __restrict__ gamma, const float* __restrict__ beta,
                        float* __restrict__ A, float* __restrict__ C, int B, int O, int nb)
{
    const int o = blockIdx.x * blockDim.x + threadIdx.x;
    if (o >= O) return;
    float s = 0.f, q = 0.f;
    for (int b = 0; b < nb; ++b) {
        s += ps[(size_t)b * O + o];
        q += pq[(size_t)b * O + o];
    }
    const float invB = 1.0f / (float)B;
    const float m = s * invB;
    const float v = fmaxf(q * invB - m * m, 0.f);
    const float a = gamma[o] * rsqrtf(v + BN_EPS);
    A[o] = a;
    C[o] = fmaf(-m, a, beta[o]);
}

__global__ __launch_bounds__(256)
void bn_apply(float* y, const float* __restrict__ A,
              const float* __restrict__ C, int O, int n4)
{
    const int stride = gridDim.x * blockDim.x;
    for (int p = blockIdx.x * blockDim.x + threadIdx.x; p < n4; p += stride) {
        float4 v = ((const float4*)y)[p];
        const int o = (p * 4) % O;
        const float4 a = *(const float4*)&A[o];
        const float4 c = *(const float4*)&C[o];
        float4 r;
        r.x = fmaf(v.x, a.x, c.x);
        r.y = fmaf(v.y, a.y, c.y);
        r.z = fmaf(v.z, a.z, c.z);
        r.w = fmaf(v.w, a.w, c.w);
        ((float4*)y)[p] = r;
    }
}

// ---------------- launch ----------------
extern "C" void kernel_launch(void* const* d_in, const int* in_sizes, int n_in,
                              void* d_out, int out_size, void* d_ws, size_t ws_size,
                              hipStream_t stream)
{
    const float* x      = (const float*)d_in[0];
    const float* scale  = (const float*)d_in[1];
    const float* bias   = (const float*)d_in[2];
    const float* weight = (const float*)d_in[3];
    const float* gamma  = (const float*)d_in[4];
    const float* beta   = (const float*)d_in[5];
    float* y = (float*)d_out;

    const int O = in_sizes[4];
    const int I = in_sizes[1] / O;
    const int B = in_sizes[0] / I;

    const int nb  = B / 64;
    const int nob = O / 64;
    const int nblocks = nb * nob;

    // ws layout (fused): bar[16 words] | part_s[nb*O] | part_q[nb*O]
    const size_t need = 64 + (size_t)2 * nb * O * sizeof(float);

    const bool fused_ok = (B % 256 == 0) && (O % 64 == 0) && (I % 128 == 0)
                       && (nblocks <= 512) && (ws_size >= need);

    if (fused_ok) {
        unsigned* bar = (unsigned*)d_ws;
        float* part_s = (float*)((char*)d_ws + 64);
        float* part_q = part_s + (size_t)nb * O;

        hipMemsetAsync(d_ws, 0, 64, stream);
        fused_kan<<<nblocks, 256, 0, stream>>>(
            x, scale, bias, weight, gamma, beta, y, bar, part_s, part_q,
            B, I, O, nob, nblocks, nb);
    } else {
        // generic fallback chain (proven r1/r7)
        float* gs = (float*)d_ws;
        float* gq = gs + O;
        float* A2 = gq + O;
        float* C2 = A2 + O;
        hipMemsetAsync(d_ws, 0, (size_t)2 * O * sizeof(float), stream);

        kan_forward<<<dim3(O / OT, B / BT), TPB, 0, stream>>>(
            x, scale, bias, weight, y, gs, gq, B, I, O);

        bn_coef<<<(O + 255) / 256, 256, 0, stream>>>(
            gs, gq, gamma, beta, A2, C2, B, O, 1);

        const int n4o = (B * O) / 4;
        const int napply = n4o < 2048 * 256 ? ((n4o + 255) / 256) : 2048;
        bn_apply<<<napply, 256, 0, stream>>>(y, A2, C2, O, n4o);
    }
}

// Round 9
// 24.044 us; speedup vs baseline: 22.0049x; 22.0049x over previous
//
#include <hip/hip_runtime.h>
#include <math.h>

#define BN_EPS 1e-5f

// ---------------- math helpers ----------------
__device__ __forceinline__ float fast_exp2(float a) {
#if __has_builtin(__builtin_amdgcn_exp2f)
    return __builtin_amdgcn_exp2f(a);
#else
    return __expf(a * 0.6931471805599453f);
#endif
}
__device__ __forceinline__ float fast_cosrev(float r) {
#if __has_builtin(__builtin_amdgcn_fractf)
    r = __builtin_amdgcn_fractf(r);
#else
    r = r - floorf(r);
#endif
#if __has_builtin(__builtin_amdgcn_cosf)
    return __builtin_amdgcn_cosf(r);
#else
    return __cosf(r * 6.283185307179586f);
#endif
}
// psi(u) = cos(5u)*exp(-u^2/2)   (validated r1-r8: absmax <= 0.031)
__device__ __forceinline__ float psi_hw(float u) {
    const float KM = 0.84932181f;            // sqrt(0.5*log2(e))
    const float KC = 0.7957747154594767f;    // 5/(2*pi)
    const float m = u * KM;
    return fast_cosrev(u * KC) * fast_exp2(-(m * m));
}

typedef __bf16 bf16x8 __attribute__((ext_vector_type(8)));
typedef float  f32x4  __attribute__((ext_vector_type(4)));

// =====================================================================
// Kernel A: one 64(b) x 64(o) tile per block, 256 threads (4 waves).
//  - fast path staged unconditionally (psi fused into bf16 staging, r5-proven)
//  - block-local uniformity check runs CONCURRENTLY (verdict used only at end)
//  - writes pre-BN y and per-block BN partial slots with PLAIN stores
//    (no atomics, no pre-zeroing; kernel boundary gives coherence)
// =====================================================================
__global__ __launch_bounds__(256)
void gemm_kan(const float* __restrict__ x, const float* __restrict__ scale,
              const float* __restrict__ bias, const float* __restrict__ weight,
              float* __restrict__ y, float* __restrict__ part_s, float* __restrict__ part_q,
              int B, int I, int O, int nob)
{
    __shared__ __align__(16) char smem[33280];   // union: bf16 tiles / f32 staging
    __shared__ float reds[4][64], redq[4][64];
    __shared__ int sbad;

    const int tid = threadIdx.x;
    const int ob  = blockIdx.x % nob;
    const int bb  = blockIdx.x / nob;
    const int O0  = ob * 64;
    const int B0  = bb * 64;
    const int lane = tid & 63;
    const int w    = tid >> 6;
    const int wm  = w >> 1, wn = w & 1;
    const int m16 = lane & 15, kg = lane >> 4;
    const int og  = tid & 15, bg = tid >> 4;

    if (tid == 0) sbad = 0;

    f32x4 accF[2][2] = {};
    unsigned bad = 0;
    bool checked = false;

    // ================= fast path staging + MFMA (unconditional) =================
    {
        __bf16* Pl = (__bf16*)smem;          // [64][128] swizzled
        __bf16* Wl = Pl + 64 * 128;

        for (int ic = 0; ic < I; ic += 128) {
            __syncthreads();
            #pragma unroll
            for (int it = 0; it < 4; ++it) {
                const int idx = tid + it * 256;
                const int row = idx >> 4;
                const int kk  = (idx & 15) * 8;
                float4 s0 = *(const float4*)&scale[(size_t)O0 * I + ic + kk];
                float4 s1 = *(const float4*)&scale[(size_t)O0 * I + ic + kk + 4];
                float4 b0 = *(const float4*)&bias [(size_t)O0 * I + ic + kk];
                float4 b1 = *(const float4*)&bias [(size_t)O0 * I + ic + kk + 4];
                float4 x0 = *(const float4*)&x[(size_t)(B0 + row) * I + ic + kk];
                float4 x1 = *(const float4*)&x[(size_t)(B0 + row) * I + ic + kk + 4];
                float4 w0 = *(const float4*)&weight[(size_t)(O0 + row) * I + ic + kk];
                float4 w1 = *(const float4*)&weight[(size_t)(O0 + row) * I + ic + kk + 4];
                bf16x8 pv, wv;
                #pragma unroll
                for (int e = 0; e < 4; ++e) {
                    const float ra = __builtin_amdgcn_rcpf(((const float*)&s0)[e]);
                    pv[e] = (__bf16)psi_hw((((const float*)&x0)[e] - ((const float*)&b0)[e]) * ra);
                    wv[e] = (__bf16)((const float*)&w0)[e];
                    const float rb = __builtin_amdgcn_rcpf(((const float*)&s1)[e]);
                    pv[e + 4] = (__bf16)psi_hw((((const float*)&x1)[e] - ((const float*)&b1)[e]) * rb);
                    wv[e + 4] = (__bf16)((const float*)&w1)[e];
                }
                unsigned byte = (unsigned)(row * 256 + kk * 2);
                byte ^= (unsigned)((row & 7) << 4);
                *reinterpret_cast<bf16x8*>(reinterpret_cast<char*>(Pl) + byte) = pv;
                *reinterpret_cast<bf16x8*>(reinterpret_cast<char*>(Wl) + byte) = wv;
            }

            // ---- concurrent uniformity check (once): rows O0..O0+63 vs row O0 ----
            if (!checked) {
                checked = true;
                const uint4* s4 = (const uint4*)scale;
                const uint4* b4 = (const uint4*)bias;
                const int i4 = I >> 2;
                const size_t base = (size_t)O0 * i4;
                for (int idx = tid; idx < 64 * i4; idx += 256) {
                    const int c = idx % i4;
                    uint4 a  = s4[base + idx], a0 = s4[base + c];
                    uint4 bv = b4[base + idx], b0 = b4[base + c];
                    bad |= (a.x^a0.x)|(a.y^a0.y)|(a.z^a0.z)|(a.w^a0.w)
                         | (bv.x^b0.x)|(bv.y^b0.y)|(bv.z^b0.z)|(bv.w^b0.w);
                }
            }
            __syncthreads();

            #pragma unroll
            for (int ks = 0; ks < 4; ++ks) {
                bf16x8 a[2], b[2];
                #pragma unroll
                for (int mi = 0; mi < 2; ++mi) {
                    const int row = wm * 32 + mi * 16 + m16;
                    unsigned byte = (unsigned)(row * 256 + ks * 64 + kg * 16);
                    byte ^= (unsigned)((row & 7) << 4);
                    a[mi] = *reinterpret_cast<const bf16x8*>(reinterpret_cast<const char*>(Pl) + byte);
                }
                #pragma unroll
                for (int ni = 0; ni < 2; ++ni) {
                    const int row = wn * 32 + ni * 16 + m16;
                    unsigned byte = (unsigned)(row * 256 + ks * 64 + kg * 16);
                    byte ^= (unsigned)((row & 7) << 4);
                    b[ni] = *reinterpret_cast<const bf16x8*>(reinterpret_cast<const char*>(Wl) + byte);
                }
                #pragma unroll
                for (int mi = 0; mi < 2; ++mi)
                    #pragma unroll
                    for (int ni = 0; ni < 2; ++ni)
                        accF[mi][ni] = __builtin_amdgcn_mfma_f32_16x16x32_bf16(
                            a[mi], b[ni], accF[mi][ni], 0, 0, 0);
            }
        }
    }

    // ---- resolve verdict ----
    if (bad) atomicOr(&sbad, 1);
    __syncthreads();

    if (sbad == 0) {
        // ---- fast path epilogue: y + BN partials ----
        #pragma unroll
        for (int mi = 0; mi < 2; ++mi) {
            const int rbase = B0 + wm * 32 + mi * 16 + kg * 4;
            #pragma unroll
            for (int ni = 0; ni < 2; ++ni) {
                const int col = O0 + wn * 32 + ni * 16 + m16;
                #pragma unroll
                for (int r = 0; r < 4; ++r)
                    y[(size_t)(rbase + r) * O + col] = accF[mi][ni][r];
            }
        }
        float s0 = 0.f, s1 = 0.f, q0 = 0.f, q1 = 0.f;
        #pragma unroll
        for (int mi = 0; mi < 2; ++mi)
            #pragma unroll
            for (int r = 0; r < 4; ++r) {
                const float v0 = accF[mi][0][r], v1 = accF[mi][1][r];
                s0 += v0; q0 += v0 * v0;
                s1 += v1; q1 += v1 * v1;
            }
        s0 += __shfl_xor(s0, 16); s0 += __shfl_xor(s0, 32);
        q0 += __shfl_xor(q0, 16); q0 += __shfl_xor(q0, 32);
        s1 += __shfl_xor(s1, 16); s1 += __shfl_xor(s1, 32);
        q1 += __shfl_xor(q1, 16); q1 += __shfl_xor(q1, 32);
        if (lane < 16) {
            reds[w][m16]      = s0;  redq[w][m16]      = q0;
            reds[w][16 + m16] = s1;  redq[w][16 + m16] = q1;
        }
        __syncthreads();
        if (tid < 64) {
            const int wn2 = tid >> 5;
            const int cw  = tid & 31;
            part_s[(size_t)bb * O + O0 + tid] = reds[wn2][cw] + reds[2 + wn2][cw];
            part_q[(size_t)bb * O + O0 + tid] = redq[wn2][cw] + redq[2 + wn2][cw];
        }
    } else {
        // ---- rare general path: per-(o,i) scale/bias (r6/r7-proven) ----
        float* xs  = (float*)smem;           // [64][33]
        float* ssm = xs + 64 * 33;           // [32][64] transposed
        float* bsm = ssm + 32 * 64;
        float* wsm = bsm + 32 * 64;
        float accG[4][4] = {};

        for (int ic = 0; ic < I; ic += 32) {
            __syncthreads();
            for (int idx = tid; idx < 512; idx += 256) {
                const int row = idx >> 3;
                const int c4  = (idx & 7) * 4;
                float4 vv = *(const float4*)&x[(size_t)(B0 + row) * I + ic + c4];
                xs[row * 33 + c4 + 0] = vv.x;
                xs[row * 33 + c4 + 1] = vv.y;
                xs[row * 33 + c4 + 2] = vv.z;
                xs[row * 33 + c4 + 3] = vv.w;
            }
            for (int idx = tid; idx < 512; idx += 256) {
                const int o  = idx >> 3;
                const int c4 = (idx & 7) * 4;
                const size_t g = (size_t)(O0 + o) * I + ic + c4;
                float4 sv = *(const float4*)&scale[g];
                float4 bv = *(const float4*)&bias[g];
                float4 wv = *(const float4*)&weight[g];
                #pragma unroll
                for (int e = 0; e < 4; ++e) {
                    ssm[(c4 + e) * 64 + o] = ((const float*)&sv)[e];
                    bsm[(c4 + e) * 64 + o] = ((const float*)&bv)[e];
                    wsm[(c4 + e) * 64 + o] = ((const float*)&wv)[e];
                }
            }
            __syncthreads();

            for (int k = 0; k < 32; ++k) {
                float xv[4];
                #pragma unroll
                for (int t = 0; t < 4; ++t) xv[t] = xs[(bg * 4 + t) * 33 + k];
                #pragma unroll
                for (int j = 0; j < 4; ++j) {
                    const int o = og * 4 + j;
                    const float sv = ssm[k * 64 + o];
                    const float bv = bsm[k * 64 + o];
                    const float wv = wsm[k * 64 + o];
                    const float rv = __builtin_amdgcn_rcpf(sv);
                    #pragma unroll
                    for (int t = 0; t < 4; ++t) {
                        const float u = (xv[t] - bv) * rv;
                        accG[t][j] = fmaf(psi_hw(u), wv, accG[t][j]);
                    }
                }
            }
        }

        #pragma unroll
        for (int t = 0; t < 4; ++t) {
            float4 vv = make_float4(accG[t][0], accG[t][1], accG[t][2], accG[t][3]);
            *(float4*)&y[(size_t)(B0 + bg * 4 + t) * O + O0 + og * 4] = vv;
        }

        float s[4], q[4];
        #pragma unroll
        for (int j = 0; j < 4; ++j) {
            s[j] = accG[0][j] + accG[1][j] + accG[2][j] + accG[3][j];
            q[j] = accG[0][j]*accG[0][j] + accG[1][j]*accG[1][j]
                 + accG[2][j]*accG[2][j] + accG[3][j]*accG[3][j];
            s[j] += __shfl_xor(s[j], 16); s[j] += __shfl_xor(s[j], 32);
            q[j] += __shfl_xor(q[j], 16); q[j] += __shfl_xor(q[j], 32);
        }
        if (lane < 16) {
            #pragma unroll
            for (int j = 0; j < 4; ++j) {
                reds[w][og * 4 + j] = s[j];
                redq[w][og * 4 + j] = q[j];
            }
        }
        __syncthreads();
        if (tid < 64) {
            part_s[(size_t)bb * O + O0 + tid] =
                reds[0][tid] + reds[1][tid] + reds[2][tid] + reds[3][tid];
            part_q[(size_t)bb * O + O0 + tid] =
                redq[0][tid] + redq[1][tid] + redq[2][tid] + redq[3][tid];
        }
    }
}

// =====================================================================
// Kernel B: per 64x64 y tile: reduce the nb partial slots for its 64 o's,
// compute A,C in LDS, apply BN to the tile (coalesced float4 r/w).
// =====================================================================
__global__ __launch_bounds__(256)
void bn_finish(const float* __restrict__ part_s, const float* __restrict__ part_q,
               const float* __restrict__ gamma, const float* __restrict__ beta,
               float* __restrict__ y, int B, int O, int nb, int nob)
{
    __shared__ float reds[4][64], redq[4][64];
    __shared__ float As[64], Cs[64];

    const int tid = threadIdx.x;
    const int ob  = blockIdx.x % nob;
    const int bb  = blockIdx.x / nob;
    const int O0  = ob * 64;
    const int B0  = bb * 64;

    // reduce partial slots: thread (st, ol) stripes over nb
    {
        const int ol = tid & 63;
        const int st = tid >> 6;
        float s = 0.f, q = 0.f;
        for (int b2 = st; b2 < nb; b2 += 4) {
            s += part_s[(size_t)b2 * O + O0 + ol];
            q += part_q[(size_t)b2 * O + O0 + ol];
        }
        reds[st][ol] = s;
        redq[st][ol] = q;
    }
    __syncthreads();
    if (tid < 64) {
        const float s = reds[0][tid] + reds[1][tid] + reds[2][tid] + reds[3][tid];
        const float q = redq[0][tid] + redq[1][tid] + redq[2][tid] + redq[3][tid];
        const float invB = 1.0f / (float)B;
        const float m = s * invB;
        const float v = fmaxf(q * invB - m * m, 0.f);
        const float a = gamma[O0 + tid] * rsqrtf(v + BN_EPS);
        As[tid] = a;
        Cs[tid] = fmaf(-m, a, beta[O0 + tid]);
    }
    __syncthreads();

    // apply: thread = (row = tid>>2, 16-col strip = (tid&3)*16)
    const int row = tid >> 2;
    const int c0  = (tid & 3) * 16;
    float* yp = &y[(size_t)(B0 + row) * O + O0 + c0];
    #pragma unroll
    for (int v4 = 0; v4 < 4; ++v4) {
        float4 v = *(float4*)&yp[v4 * 4];
        const int cc = c0 + v4 * 4;
        float4 r;
        r.x = fmaf(v.x, As[cc + 0], Cs[cc + 0]);
        r.y = fmaf(v.y, As[cc + 1], Cs[cc + 1]);
        r.z = fmaf(v.z, As[cc + 2], Cs[cc + 2]);
        r.w = fmaf(v.w, As[cc + 3], Cs[cc + 3]);
        *(float4*)&yp[v4 * 4] = r;
    }
}

// =====================================================================
// Shape fallback (non-divisible): round-1 proven general kernel + BN chain
// =====================================================================
constexpr int BT  = 128;
constexpr int OT  = 32;
constexpr int IC  = 64;
constexpr int TPB = 512;
constexpr int LDR = IC + 4;

__global__ __launch_bounds__(TPB, 4)
void kan_forward(const float* __restrict__ x, const float* __restrict__ scale,
                 const float* __restrict__ bias, const float* __restrict__ weight,
                 float* __restrict__ y, float* __restrict__ gsum,
                 float* __restrict__ gsq, int B, int I, int O)
{
    __shared__ __align__(16) float xs[BT][LDR];
    __shared__ __align__(16) float pr[OT][LDR];
    __shared__ __align__(16) float pc[OT][LDR];
    __shared__ __align__(16) float pw[OT][LDR];

    const int tid = threadIdx.x;
    const int og  = tid & 15;
    const int bg  = tid >> 4;
    const int O0  = blockIdx.x * OT;
    const int B0  = blockIdx.y * BT;

    float acc[4][2] = {{0.f,0.f},{0.f,0.f},{0.f,0.f},{0.f,0.f}};

    for (int ic = 0; ic < I; ic += IC) {
        __syncthreads();
        for (int r = tid; r < BT * (IC/4); r += TPB) {
            const int row = r >> 4;
            const int c4  = (r & 15) * 4;
            float4 v = *(const float4*)&x[(size_t)(B0+row)*I + ic + c4];
            *(float4*)&xs[row][c4] = v;
        }
        for (int r = tid; r < OT * (IC/4); r += TPB) {
            const int row = r >> 4;
            const int c4  = (r & 15) * 4;
            const size_t g = (size_t)(O0+row)*I + ic + c4;
            float4 sv = *(const float4*)&scale[g];
            float4 bv = *(const float4*)&bias[g];
            float4 wv = *(const float4*)&weight[g];
            float4 rv, cv;
            rv.x = 1.0f/sv.x; rv.y = 1.0f/sv.y; rv.z = 1.0f/sv.z; rv.w = 1.0f/sv.w;
            cv.x = -bv.x*rv.x; cv.y = -bv.y*rv.y; cv.z = -bv.z*rv.z; cv.w = -bv.w*rv.w;
            *(float4*)&pr[row][c4] = rv;
            *(float4*)&pc[row][c4] = cv;
            *(float4*)&pw[row][c4] = wv;
        }
        __syncthreads();

        #pragma unroll 2
        for (int i = 0; i < IC; i += 4) {
            float4 xv[4];
            #pragma unroll
            for (int k = 0; k < 4; ++k)
                xv[k] = *(const float4*)&xs[bg*4+k][i];
            #pragma unroll
            for (int j = 0; j < 2; ++j) {
                const int o = og*2 + j;
                const float4 rv = *(const float4*)&pr[o][i];
                const float4 cv = *(const float4*)&pc[o][i];
                const float4 wv = *(const float4*)&pw[o][i];
                #pragma unroll
                for (int k = 0; k < 4; ++k) {
                    #pragma unroll
                    for (int e = 0; e < 4; ++e) {
                        const float u = fmaf(((const float*)&xv[k])[e],
                                             ((const float*)&rv)[e], ((const float*)&cv)[e]);
                        acc[k][j] = fmaf(psi_hw(u), ((const float*)&wv)[e], acc[k][j]);
                    }
                }
            }
        }
    }

    #pragma unroll
    for (int k = 0; k < 4; ++k) {
        float2 v = make_float2(acc[k][0], acc[k][1]);
        *(float2*)&y[(size_t)(B0 + bg*4 + k)*O + O0 + og*2] = v;
    }

    float s[2], q[2];
    #pragma unroll
    for (int j = 0; j < 2; ++j) {
        s[j] = acc[0][j]+acc[1][j]+acc[2][j]+acc[3][j];
        q[j] = acc[0][j]*acc[0][j]+acc[1][j]*acc[1][j]
             + acc[2][j]*acc[2][j]+acc[3][j]*acc[3][j];
        s[j] += __shfl_xor(s[j], 16); s[j] += __shfl_xor(s[j], 32);
        q[j] += __shfl_xor(q[j], 16); q[j] += __shfl_xor(q[j], 32);
    }
    __syncthreads();
    float* red = &xs[0][0];
    const int wave = tid >> 6;
    const int lane = tid & 63;
    if (lane < 16) {
        red[      wave*32 + og*2 + 0] = s[0];
        red[      wave*32 + og*2 + 1] = s[1];
        red[256 + wave*32 + og*2 + 0] = q[0];
        red[256 + wave*32 + og*2 + 1] = q[1];
    }
    __syncthreads();
    if (tid < OT) {
        float ss = 0.f, qq = 0.f;
        #pragma unroll
        for (int w2 = 0; w2 < TPB/64; ++w2) {
            ss += red[      w2*32 + tid];
            qq += red[256 + w2*32 + tid];
        }
        atomicAdd(&gsum[O0 + tid], ss);
        atomicAdd(&gsq [O0 + tid], qq);
    }
}

__global__ void bn_coef(const float* __restrict__ ps, const float* __restrict__ pq,
                        const float* __restrict__ gamma, const float* __restrict__ beta,
                        float* __restrict__ A, float* __restrict__ C, int B, int O, int nb)
{
    const int o = blockIdx.x * blockDim.x + threadIdx.x;
    if (o >= O) return;
    float s = 0.f, q = 0.f;
    for (int b = 0; b < nb; ++b) {
        s += ps[(size_t)b * O + o];
        q += pq[(size_t)b * O + o];
    }
    const float invB = 1.0f / (float)B;
    const float m = s * invB;
    const float v = fmaxf(q * invB - m * m, 0.f);
    const float a = gamma[o] * rsqrtf(v + BN_EPS);
    A[o] = a;
    C[o] = fmaf(-m, a, beta[o]);
}

__global__ __launch_bounds__(256)
void bn_apply(float* y, const float* __restrict__ A,
              const float* __restrict__ C, int O, int n4)
{
    const int stride = gridDim.x * blockDim.x;
    for (int p = blockIdx.x * blockDim.x + threadIdx.x; p < n4; p += stride) {
        float4 v = ((const float4*)y)[p];
        const int o = (p * 4) % O;
        const float4 a = *(const float4*)&A[o];
        const float4 c = *(const float4*)&C[o];
        float4 r;
        r.x = fmaf(v.x, a.x, c.x);
        r.y = fmaf(v.y, a.y, c.y);
        r.z = fmaf(v.z, a.z, c.z);
        r.w = fmaf(v.w, a.w, c.w);
        ((float4*)y)[p] = r;
    }
}

// ---------------- launch ----------------
extern "C" void kernel_launch(void* const* d_in, const int* in_sizes, int n_in,
                              void* d_out, int out_size, void* d_ws, size_t ws_size,
                              hipStream_t stream)
{
    const float* x      = (const float*)d_in[0];
    const float* scale  = (const float*)d_in[1];
    const float* bias   = (const float*)d_in[2];
    const float* weight = (const float*)d_in[3];
    const float* gamma  = (const float*)d_in[4];
    const float* beta   = (const float*)d_in[5];
    float* y = (float*)d_out;

    const int O = in_sizes[4];
    const int I = in_sizes[1] / O;
    const int B = in_sizes[0] / I;

    const int nb  = B / 64;
    const int nob = O / 64;

    // ws layout: part_s[nb*O] | part_q[nb*O]  (no control words, no memset)
    const size_t need = (size_t)2 * nb * O * sizeof(float);

    const bool main_ok = (B % 64 == 0) && (O % 64 == 0) && (I % 128 == 0)
                      && (ws_size >= need);

    if (main_ok) {
        float* part_s = (float*)d_ws;
        float* part_q = part_s + (size_t)nb * O;

        gemm_kan<<<nb * nob, 256, 0, stream>>>(
            x, scale, bias, weight, y, part_s, part_q, B, I, O, nob);

        bn_finish<<<nb * nob, 256, 0, stream>>>(
            part_s, part_q, gamma, beta, y, B, O, nb, nob);
    } else {
        // generic fallback chain (proven r1/r7)
        float* gs = (float*)d_ws;
        float* gq = gs + O;
        float* A2 = gq + O;
        float* C2 = A2 + O;
        hipMemsetAsync(d_ws, 0, (size_t)2 * O * sizeof(float), stream);

        kan_forward<<<dim3(O / OT, B / BT), TPB, 0, stream>>>(
            x, scale, bias, weight, y, gs, gq, B, I, O);

        bn_coef<<<(O + 255) / 256, 256, 0, stream>>>(
            gs, gq, gamma, beta, A2, C2, B, O, 1);

        const int n4o = (B * O) / 4;
        const int napply = n4o < 2048 * 256 ? ((n4o + 255) / 256) : 2048;
        bn_apply<<<napply, 256, 0, stream>>>(y, A2, C2, O, n4o);
    }
}